// Round 1
// 191.790 us; speedup vs baseline: 1.0008x; 1.0008x over previous
//
#include <hip/hip_runtime.h>

// Problem constants: mask_pred (32,16,256,256) f32, pos_gt (32,16,4) int.
constexpr int Wd  = 256;
constexpr int Hd  = 256;
constexpr int BRn = 512;                         // 32*16 images
constexpr long long NTOT = (long long)BRn * Hd * Wd;   // 33,554,432
constexpr int F4_PER_IMG   = Hd * Wd / 4;        // 16384 float4 per image
constexpr int CHUNKS       = 8;                  // blocks per image
constexpr int F4_PER_CHUNK = F4_PER_IMG / CHUNKS;// 2048 float4 = 32 rows
constexpr int TPB          = 256;
constexpr int ITERS        = F4_PER_CHUNK / TPB; // 8 float4 per thread
constexpr int NBLOCKS      = BRn * CHUNKS;       // 4096 partials

// R5: keep R3's proven block-chunked 32KB layout + batched loads.
// New: exploit that each wave covers exactly ONE row per j-iteration
// (64 lanes x 4 floats = 256 = W). Row predicate -> scalar branch via
// readfirstlane; column predicates are j-invariant per lane -> hoisted.
// ~85% of waves take the short log(1-p)-only body (rows outside box).

__global__ __launch_bounds__(TPB)
void crop_ce_partial(const float* __restrict__ mp,
                     const int* __restrict__ pg,
                     float* __restrict__ partials) {
    const int img   = blockIdx.x;    // which (b,r) image
    const int chunk = blockIdx.y;    // which 1/8 of the image (32 rows)
    const float4* b4 = (const float4*)(mp + (size_t)img * (Hd * Wd));
    const int y0 = pg[img * 4 + 0];
    const int x0 = pg[img * 4 + 1];
    const int y1 = pg[img * 4 + 2];
    const int x1 = pg[img * 4 + 3];

    // Issue all loads back-to-back (8 float4 in flight per wave).
    float4 v[ITERS];
#pragma unroll
    for (int j = 0; j < ITERS; ++j) {
        const int i4 = chunk * F4_PER_CHUNK + j * TPB + (int)threadIdx.x;
        v[j] = b4[i4];
    }

    const int wid  = (int)threadIdx.x >> 6;
    const int lane = (int)threadIdx.x & 63;
    const int col  = lane << 2;            // this lane's column (j-invariant)
    const int rowBase = chunk * 32 + wid;  // row for iter j is rowBase + 4*j

    // Column membership per lane, invariant across j — hoisted out of loop.
    const bool cin0 = (col     >= x0) & (col     <= x1);
    const bool cin1 = (col + 1 >= x0) & (col + 1 <= x1);
    const bool cin2 = (col + 2 >= x0) & (col + 2 <= x1);
    const bool cin3 = (col + 3 >= x0) & (col + 3 <= x1);

    float acc = 0.f;
    const int blkRow0 = chunk * 32;
    const int blkRow1 = chunk * 32 + 31;

    if (y0 > blkRow1 || y1 < blkRow0) {
        // Entire block outside the box (also covers empty boxes y0>y1):
        // pure log(1-p) stream, no per-element predicates at all.
#pragma unroll
        for (int j = 0; j < ITERS; ++j) {
            acc += __logf(1.f - v[j].x) + __logf(1.f - v[j].y)
                 + __logf(1.f - v[j].z) + __logf(1.f - v[j].w);
        }
    } else {
#pragma unroll
        for (int j = 0; j < ITERS; ++j) {
            const int row = rowBase + 4 * j;           // wave-uniform
            const int rin = (row >= y0) & (row <= y1); // uniform predicate
            if (__builtin_amdgcn_readfirstlane(rin)) { // scalar branch
                const float a0 = cin0 ? v[j].x : 1.f - v[j].x;
                const float a1 = cin1 ? v[j].y : 1.f - v[j].y;
                const float a2 = cin2 ? v[j].z : 1.f - v[j].z;
                const float a3 = cin3 ? v[j].w : 1.f - v[j].w;
                acc += __logf(a0) + __logf(a1) + __logf(a2) + __logf(a3);
            } else {
                acc += __logf(1.f - v[j].x) + __logf(1.f - v[j].y)
                     + __logf(1.f - v[j].z) + __logf(1.f - v[j].w);
            }
        }
    }

    // wave-64 shuffle reduction
    for (int off = 32; off; off >>= 1) acc += __shfl_down(acc, off);
    __shared__ float wpart[TPB / 64];
    if (lane == 0) wpart[wid] = acc;
    __syncthreads();

    if (threadIdx.x == 0) {
        float bs = 0.f;
        for (int k = 0; k < TPB / 64; ++k) bs += wpart[k];
        // plain store — no contention, no pre-zero required (all slots written)
        partials[blockIdx.y * BRn + blockIdx.x] = bs;
    }
}

__global__ __launch_bounds__(TPB)
void crop_ce_final(const float* __restrict__ partials,
                   float* __restrict__ out) {
    // single block: reduce NBLOCKS floats in double, float4 loads
    const float4* p4 = (const float4*)partials;
    double acc = 0.0;
#pragma unroll
    for (int j = 0; j < NBLOCKS / 4 / TPB; ++j) {   // 4 iterations
        const float4 v = p4[j * TPB + (int)threadIdx.x];
        acc += (double)v.x + (double)v.y + (double)v.z + (double)v.w;
    }

    for (int off = 32; off; off >>= 1) acc += __shfl_down(acc, off);
    __shared__ double wpart[TPB / 64];
    const int lane = threadIdx.x & 63;
    const int wid  = threadIdx.x >> 6;
    if (lane == 0) wpart[wid] = acc;
    __syncthreads();

    if (threadIdx.x == 0) {
        double total = 0.0;
        for (int k = 0; k < TPB / 64; ++k) total += wpart[k];
        out[0] = (float)(-total / (double)NTOT);
    }
}

extern "C" void kernel_launch(void* const* d_in, const int* in_sizes, int n_in,
                              void* d_out, int out_size, void* d_ws, size_t ws_size,
                              hipStream_t stream) {
    const float* mp  = (const float*)d_in[0];
    const int*   pg  = (const int*)d_in[1];
    float* out       = (float*)d_out;
    float* partials  = (float*)d_ws;   // NBLOCKS floats, fully overwritten each launch

    dim3 grid(BRn, CHUNKS);
    crop_ce_partial<<<grid, TPB, 0, stream>>>(mp, pg, partials);
    crop_ce_final<<<1, TPB, 0, stream>>>(partials, out);
}